// Round 2
// baseline (365.417 us; speedup 1.0000x reference)
//
#include <hip/hip_runtime.h>
#include <math.h>

using uint = unsigned int;
typedef _Float16 h2    __attribute__((ext_vector_type(2)));
typedef _Float16 f16x8 __attribute__((ext_vector_type(8)));
typedef float    f32x4 __attribute__((ext_vector_type(4)));

#define N_ATOMS 8192
#define NEDGE   262144
#define KNBR    32
#define NGAUSS  50
#define NLAYER  6
#define NB      32
#define GTAB    1024
#define DMAX    8.6603f
#define FCUT    10.0f
#define MB      1048576

#define NSETUP  512
#define NTABLE  192
#define NGRID   (NSETUP + NTABLE)

// ---- k_setup legacy LDS geometry (stride 76) ----
#define LSTRIDE 76
#define S_WT    0               // 128*76 = 9728
#define S_AS    9728            // 16*76 = 1216

// ---- k_fused swizzled LDS geometry (stride 64, quad ^= row&15) ----
#define WA_OFF  0               // 8192 uints (32 KB)
#define WB_OFF  8192            // 8192
#define AS_OFF  16384           // 1024 (16 rows x 64)
#define TS_OFF  17408           // 1024
#define LAY_N   18432           // 72 KB -> exactly 2 blocks/CU, 512 co-resident

// ---- table LDS (merged into k_setup; union with setup regions) ----
#define T_W1    0               // 4096
#define T_W2    4096            // 8192
#define T_RBF   12288           // 1024
#define T_HID   13312           // 2048
#define TAB_SMEM 15360          // 60 KB, covers setup's 10944 too

// wpack layout (uints): 18 mats 128x128 (c,kp): cf1 x6 | cf2 x6 | int x6, then ow1^T
#define OW1P_OFF 147456
#define PACK_END 151552         // mlp_w1/w2 no longer packed (table reads raw)
#define X_STR    524288         // 2 MB of uints per per-layer x buffer

__device__ __forceinline__ float ssp(float x) {
    return fmaxf(x, 0.0f) + log1pf(expf(-fabsf(x))) - 0.69314718055994531f;
}
__device__ __forceinline__ uint pack2(float a, float b) {
    union { h2 h; uint u; } x;
    h2 v; v.x = (_Float16)a; v.y = (_Float16)b; x.h = v; return x.u;
}
__device__ __forceinline__ h2 u2h(uint u) {
    union { uint u; h2 h; } x; x.u = u; return x.h;
}
__device__ __forceinline__ uint h2u(h2 h) {
    union { h2 h; uint u; } x; x.h = h; return x.u;
}
__device__ __forceinline__ float fdot2f(h2 a, h2 b, float c) {
#if __has_builtin(__builtin_amdgcn_fdot2)
    return __builtin_amdgcn_fdot2(a, b, c, false);
#else
    return fmaf((float)a.y, (float)b.y, fmaf((float)a.x, (float)b.x, c));
#endif
}

// ---- swizzled indexing: row-stride 64 uints, bank quad XORed with row&15 ----
__device__ __forceinline__ int swz(int row, int quad) {
    return row * 64 + ((quad ^ (row & 15)) << 2);
}
__device__ __forceinline__ int swzc(int row, int c) {   // c = uint column 0..63
    return row * 64 + (((c >> 2) ^ (row & 15)) << 2) + (c & 3);
}

// stage pre-packed W^T (c,kp) -> swizzled LDS region
__device__ __forceinline__ void stage_sw(uint* dst, const uint* __restrict__ src,
                                         int n16, int tid) {
    for (int i = tid; i < n16; i += 256) {
        uint4 v = ((const uint4*)src)[i];
        *(uint4*)&dst[swz(i >> 4, i & 15)] = v;
    }
}

// swizzled MFMA: D[16 rows][NCT*16 cols] = A(16x128) @ W^T, cols base nb
template<int NCT>
__device__ __forceinline__ void run_gemm_sw(const uint* smA, const uint* smW,
                                            int lane, int nb, f32x4* acc) {
    int m = lane & 15, q = lane >> 4;
    #pragma unroll
    for (int ks = 0; ks < 4; ++ks) {
        int cq = q + ks * 4;
        f16x8 a = *(const f16x8*)&smA[swz(m, cq)];
        #pragma unroll
        for (int ct = 0; ct < NCT; ++ct) {
            int n = nb + ct * 16 + m;
            f16x8 b = *(const f16x8*)&smW[swz(n, cq)];
            acc[ct] = __builtin_amdgcn_mfma_f32_16x16x32_f16(a, b, acc[ct], 0, 0, 0);
        }
    }
}

// legacy stride-76 gemm for k_setup x0
template<int NCT>
__device__ __forceinline__ void run_gemm(const uint* sm, int as_off, int lane,
                                         int nb, f32x4* acc) {
    int m = lane & 15, q = lane >> 4;
    #pragma unroll
    for (int ks = 0; ks < 4; ++ks) {
        f16x8 a = *(const f16x8*)&sm[as_off + m * LSTRIDE + q * 4 + ks * 16];
        #pragma unroll
        for (int ct = 0; ct < NCT; ++ct) {
            f16x8 b = *(const f16x8*)&sm[S_WT + (nb + ct * 16 + m) * LSTRIDE + q * 4 + ks * 16];
            acc[ct] = __builtin_amdgcn_mfma_f32_16x16x32_f16(a, b, acc[ct], 0, 0, 0);
        }
    }
}

struct SArgs {
    const float *pos; const int *z; const int *ei; const int *dom;
    const float *emb;
    const float *cf1; const float *cf2w; const float *intw; const float *ow1;
    const float *mw1; const float *mw2; const float *mb1; const float *mb2;
    const float *dome; const float *fw1; const float *fb1;
    const float *fw2; const float *fb2; const float *bw; const float *bb;
    uint2 *epack; float *h; uint *xA;
    float *gbias; uint *wpack; uint *tab2; uint *bar;
    float *out; int out_size;
};

// ---------------------------------------------------------------------------
// merged setup: zero-out + wcvt + epack + embed + x0 GEMM + film (blocks 0..511)
//               + filter-table build (blocks 512..703, packs mlp weights inline
//               so it has NO dependency on wpack and overlaps the setup blocks)
__global__ void __launch_bounds__(256) k_setup(SArgs a) {
    __shared__ __align__(16) uint sm[TAB_SMEM];
    const int tid = threadIdx.x, bid = blockIdx.x;
    const int gidx = bid * 256 + tid, gsz = NGRID * 256;
    const int lane = tid & 63, w = tid >> 6;
    const int m = lane & 15, q = lane >> 4;

    for (int i = gidx; i < a.out_size; i += gsz) a.out[i] = 0.0f;
    if (gidx < 256) a.bar[gidx] = 0u;      // per-graph barrier counters

    for (int idx = gidx; idx < PACK_END; idx += gsz) {
        if (idx < OW1P_OFF) {
            int mat = idx >> 13, e = idx & 8191;
            int kp = e >> 7, cc = e & 127;
            const float* src = (mat < 6) ? (a.cf1 + mat * 16384)
                            : (mat < 12) ? (a.cf2w + (mat - 6) * 16384)
                                         : (a.intw + (mat - 12) * 16384);
            a.wpack[mat * 8192 + cc * 64 + kp] =
                pack2(src[2 * kp * 128 + cc], src[(2 * kp + 1) * 128 + cc]);
        } else {
            int e = idx - OW1P_OFF;
            int kp = e >> 6, cc = e & 63;
            a.wpack[OW1P_OFF + cc * 64 + kp] =
                pack2(a.ow1[2 * kp * 64 + cc], a.ow1[(2 * kp + 1) * 64 + cc]);
        }
    }

    if (bid < NSETUP) {
        const int rowbase = bid * 16;
        const float invdelta = (float)(GTAB - 1) / DMAX;
        #pragma unroll
        for (int t = 0; t < 2; ++t) {
            int e = rowbase * KNBR + t * 256 + tid;
            int s = a.ei[e], d = a.ei[NEDGE + e];
            float dx = a.pos[3*s] - a.pos[3*d];
            float dy = a.pos[3*s+1] - a.pos[3*d+1];
            float dz = a.pos[3*s+2] - a.pos[3*d+2];
            float dist = sqrtf(dx*dx + dy*dy + dz*dz);
            float u = dist * invdelta;
            int i0 = (int)u; i0 = (i0 < GTAB - 2) ? i0 : (GTAB - 2);
            float t2 = u - (float)i0;
            uint tb = pack2(t2, 0.0f) & 0xffffu;
            uint2 ep; ep.x = (uint)s; ep.y = (tb << 16) | (uint)i0;
            a.epack[e] = ep;
        }

        for (int i = tid; i < 1024; i += 256) {
            int r = i >> 6, f2 = i & 63;
            int zz = a.z[rowbase + r];
            float2 v = *(const float2*)&a.emb[zz * 128 + f2 * 2];
            *(float2*)&a.h[(rowbase + r) * 128 + f2 * 2] = v;
            sm[S_AS + r * LSTRIDE + f2] = pack2(v.x, v.y);
        }
        for (int i = tid; i < 2048; i += 256) {
            int m4 = i >> 7, cc = i & 127;
            float v[8];
            #pragma unroll
            for (int j = 0; j < 8; ++j) v[j] = a.cf1[(8 * m4 + j) * 128 + cc];
            uint4 pk; pk.x = pack2(v[0], v[1]); pk.y = pack2(v[2], v[3]);
            pk.z = pack2(v[4], v[5]); pk.w = pack2(v[6], v[7]);
            *(uint4*)&sm[cc * LSTRIDE + m4 * 4] = pk;
        }
        __syncthreads();
        {   // x0 = h @ W1_0 -> xA
            f32x4 acc[2] = {{0,0,0,0},{0,0,0,0}};
            run_gemm<2>(sm, S_AS, lane, w * 32, acc);
            #pragma unroll
            for (int ct = 0; ct < 2; ++ct) {
                int n = w * 32 + ct * 16 + m;
                #pragma unroll
                for (int i = 0; i < 4; ++i) {
                    float v = acc[ct][i];
                    float u = __shfl_xor(v, 1, 64);
                    if (!(lane & 1))
                        a.xA[(rowbase + q * 4 + i) * 64 + (n >> 1)] = pack2(v, u);
                }
            }
        }
        __syncthreads();
        if (bid >= 32 && bid < 64) {
            int g = bid - 32;
            float* fs = (float*)sm;
            if (tid < 64) fs[tid] = a.dome[a.dom[g] * 64 + tid];
            __syncthreads();
            if (tid < 128) {
                float acc = a.fb1[tid];
                for (int i = 0; i < 64; ++i) acc = fmaf(fs[i], a.fw1[i*128 + tid], acc);
                fs[64 + tid] = fmaxf(acc, 0.0f);
            }
            __syncthreads();
            if (tid < 128) {
                float acc = a.fb2[tid];
                for (int i = 0; i < 128; ++i) acc = fmaf(fs[64+i], a.fw2[i*128 + tid], acc);
                fs[192 + tid] = acc;
            }
            __syncthreads();
            if (tid < 128) {
                float acc = a.bb[tid];
                for (int i = 0; i < 128; ++i) acc = fmaf(fs[192+i], a.bw[i*128 + tid], acc);
                #pragma unroll
                for (int off = 32; off > 0; off >>= 1) acc += __shfl_down(acc, off, 64);
                if ((tid & 63) == 0) fs[320 + (tid >> 6)] = acc;
            }
            __syncthreads();
            if (tid == 0) a.gbias[g] = fs[320] + fs[321];
        }
    } else {
        // ---- filter tables (formerly k_table), packs mlp_w1/w2 from raw floats ----
        const int tb = bid - NSETUP;
        const int l = tb >> 5;
        const int base = (tb & 31) * 32;
        for (int i = tid; i < 4096; i += 256) {      // W1 (kp,c), kp 0..31
            int kp = i >> 7, cc = i & 127, g0 = 2 * kp;
            float va = (g0 < NGAUSS)     ? a.mw1[l*NGAUSS*128 + g0*128 + cc]     : 0.f;
            float vb = (g0 + 1 < NGAUSS) ? a.mw1[l*NGAUSS*128 + (g0+1)*128 + cc] : 0.f;
            sm[T_W1 + i] = pack2(va, vb);
        }
        for (int i = tid; i < 8192; i += 256) {      // W2 (kp,c), kp 0..63
            int kp = i >> 7, cc = i & 127;
            sm[T_W2 + i] = pack2(a.mw2[l*16384 + 2*kp*128 + cc],
                                 a.mw2[l*16384 + (2*kp+1)*128 + cc]);
        }
        const float delta = DMAX / (float)(GTAB - 1);
        const float gstep = FCUT / (float)(NGAUSS - 1);
        const float coeff = -0.5f / (gstep * gstep);
        for (int i = tid; i < 1024; i += 256) {
            int r = i >> 5, kp = i & 31;
            float dv = (float)(base + r) * delta;
            int g0 = 2 * kp;
            float v0 = 0.f, v1 = 0.f;
            if (g0 < NGAUSS)     { float t = dv - (float)g0 * gstep;     v0 = expf(coeff*t*t); }
            if (g0 + 1 < NGAUSS) { float t = dv - (float)(g0+1) * gstep; v1 = expf(coeff*t*t); }
            sm[T_RBF + i] = pack2(v0, v1);
        }
        __syncthreads();
        int tx = tid & 31, ty = tid >> 5, c0 = tx * 4, tr0 = ty * 4;
        float acc[4][4];
        #pragma unroll
        for (int i = 0; i < 4; ++i) { acc[i][0]=0.f; acc[i][1]=0.f; acc[i][2]=0.f; acc[i][3]=0.f; }
        #pragma unroll
        for (int oct = 0; oct < 8; ++oct) {
            int kp0 = oct * 4;
            uint4 w_[4];
            #pragma unroll
            for (int p = 0; p < 4; ++p) w_[p] = *(const uint4*)&sm[T_W1 + (kp0+p)*128 + c0];
            #pragma unroll
            for (int i = 0; i < 4; ++i) {
                uint4 av = *(const uint4*)&sm[T_RBF + (tr0+i)*32 + kp0];
                uint aa[4] = {av.x, av.y, av.z, av.w};
                #pragma unroll
                for (int p = 0; p < 4; ++p) {
                    h2 ap = u2h(aa[p]);
                    acc[i][0] = fdot2f(ap, u2h(w_[p].x), acc[i][0]);
                    acc[i][1] = fdot2f(ap, u2h(w_[p].y), acc[i][1]);
                    acc[i][2] = fdot2f(ap, u2h(w_[p].z), acc[i][2]);
                    acc[i][3] = fdot2f(ap, u2h(w_[p].w), acc[i][3]);
                }
            }
        }
        float4 b1v = *(const float4*)&a.mb1[l*128 + c0];
        #pragma unroll
        for (int i = 0; i < 4; ++i) {
            uint2 o;
            o.x = pack2(ssp(acc[i][0] + b1v.x), ssp(acc[i][1] + b1v.y));
            o.y = pack2(ssp(acc[i][2] + b1v.z), ssp(acc[i][3] + b1v.w));
            *(uint2*)&sm[T_HID + (tr0+i)*64 + (c0 >> 1)] = o;
        }
        __syncthreads();
        float acc2[4][4];
        #pragma unroll
        for (int i = 0; i < 4; ++i) { acc2[i][0]=0.f; acc2[i][1]=0.f; acc2[i][2]=0.f; acc2[i][3]=0.f; }
        #pragma unroll 4
        for (int oct = 0; oct < 16; ++oct) {
            int kp0 = oct * 4;
            uint4 w_[4];
            #pragma unroll
            for (int p = 0; p < 4; ++p) w_[p] = *(const uint4*)&sm[T_W2 + (kp0+p)*128 + c0];
            #pragma unroll
            for (int i = 0; i < 4; ++i) {
                uint4 av = *(const uint4*)&sm[T_HID + (tr0+i)*64 + kp0];
                uint aa[4] = {av.x, av.y, av.z, av.w};
                #pragma unroll
                for (int p = 0; p < 4; ++p) {
                    h2 ap = u2h(aa[p]);
                    acc2[i][0] = fdot2f(ap, u2h(w_[p].x), acc2[i][0]);
                    acc2[i][1] = fdot2f(ap, u2h(w_[p].y), acc2[i][1]);
                    acc2[i][2] = fdot2f(ap, u2h(w_[p].z), acc2[i][2]);
                    acc2[i][3] = fdot2f(ap, u2h(w_[p].w), acc2[i][3]);
                }
            }
        }
        float4 b2v = *(const float4*)&a.mb2[l*128 + c0];
        #pragma unroll
        for (int i = 0; i < 4; ++i) {
            int row = base + tr0 + i;
            float dv = (float)row * delta;
            float Cd = 0.5f * (cosf(dv * 0.3141592653589793f) + 1.0f);
            uint2 o;
            o.x = pack2((acc2[i][0] + b2v.x)*Cd, (acc2[i][1] + b2v.y)*Cd);
            o.y = pack2((acc2[i][2] + b2v.z)*Cd, (acc2[i][3] + b2v.w)*Cd);
            *(uint2*)&a.tab2[(l*GTAB + row)*128 + tx*4] = o;
            if (row > 0)
                *(uint2*)&a.tab2[(l*GTAB + row - 1)*128 + tx*4 + 2] = o;
        }
    }
}

struct LArgs {
    const float* h;
    const uint* x0;
    uint* xb;                 // x_1..x_5, X_STR uints apart
    const uint* tab2;
    const uint2* epack;
    const uint* wpack;
    const float* cf2b;
    const float* intb;
    const float* ob1; const float* ow2; const float* ob2;
    const float* gbias;
    float* out;
    uint* bar;                // [NLAYER-1][NB] arrive counters, zeroed by k_setup
};

// ---------------------------------------------------------------------------
// All 6 layers fused, REGULAR launch (cooperative launch failed under the
// harness -> round-1 all-zeros output). Co-residency is structural: 72 KB LDS
// -> exactly 2 blocks/CU x 256 CU = 512 = grid, and __launch_bounds__(256,2)
// caps VGPRs at 256 so registers can't reduce it. Between layers only the 16
// blocks of a graph synchronize: release-add (lowered with buffer_wbl2 sc1 at
// agent scope, pushing the x stores — already drained to L2 by __syncthreads —
// to the agent-coherent point), relaxed bounded spin (no per-poll L2-inv
// storm), then ONE acquire fence (buffer_inv sc1) before consuming. Spin is
// bounded so a violated residency assumption fails finite instead of hanging.
// h lives in registers for the whole kernel; never round-trips global.
__global__ void __launch_bounds__(256, 2) k_fused(LArgs a) {
    __shared__ __align__(16) uint sm[LAY_N];
    const int tid = threadIdx.x, bid = blockIdx.x;
    const int lane = tid & 63, w = tid >> 6;
    const int m = lane & 15, q = lane >> 4;
    const int xcd = bid & 7;
    const int j   = bid >> 3;
    const int g   = xcd * 4 + (j >> 4);
    const int sub = j & 15;
    const int rowbase = g * 256 + sub * 16;

    float hr[2][4];
    #pragma unroll
    for (int ct = 0; ct < 2; ++ct)
        #pragma unroll
        for (int i = 0; i < 4; ++i)
            hr[ct][i] = a.h[(rowbase + q * 4 + i) * 128 + w * 32 + ct * 16 + m];

    const uint* xr = a.x0;
    uint* xw = a.xb;

    #pragma unroll 1
    for (int l = 0; l < NLAYER; ++l) {
        const bool last = (l == NLAYER - 1);
        const uint* w2p  = a.wpack + (6 + l) * 8192;
        const uint* w3p  = a.wpack + (12 + l) * 8192;
        const uint* w1np = last ? (a.wpack + OW1P_OFF) : (a.wpack + (l + 1) * 8192);
        const uint* tabl = a.tab2 + l * (GTAB * 128);
        const float* b2 = a.cf2b + l * 128;
        const float* b3 = a.intb + l * 128;

        stage_sw(&sm[WA_OFF], w2p, 2048, tid);     // W2 loads fly under gather
        {   // gather 16 atoms (4/wave), 2 edges/iter per 32-lane side
            const int side = lane >> 5, l5 = lane & 31;
            #pragma unroll
            for (int p = 0; p < 4; ++p) {
                int al = p * 4 + w;
                uint2 ep = a.epack[(rowbase + al) * KNBR + l5];
                h2 a0; a0.x = (_Float16)0; a0.y = (_Float16)0;
                h2 a1 = a0;
                #pragma unroll 4
                for (int k = 0; k < 16; ++k) {
                    int e = 2 * k + side;
                    uint s = __shfl(ep.x, e, 64);
                    uint y = __shfl(ep.y, e, 64);
                    int i0 = (int)(y & 0xffffu);
                    uint th = y >> 16;
                    h2 t2 = u2h(th | (th << 16));
                    uint4 tv = *(const uint4*)&tabl[i0 * 128 + l5 * 4];
                    uint2 xv = *(const uint2*)&xr[(int)s * 64 + l5 * 2];
                    h2 w0 = u2h(tv.x) + t2 * (u2h(tv.z) - u2h(tv.x));
                    h2 w1 = u2h(tv.y) + t2 * (u2h(tv.w) - u2h(tv.y));
                    a0 = a0 + u2h(xv.x) * w0;
                    a1 = a1 + u2h(xv.y) * w1;
                }
                uint u0 = h2u(a0), u1 = h2u(a1);
                uint p0 = __shfl_xor(u0, 32, 64), p1 = __shfl_xor(u1, 32, 64);
                if (side == 0) {
                    h2 r0 = u2h(u0) + u2h(p0), r1 = u2h(u1) + u2h(p1);
                    uint2 o; o.x = h2u(r0); o.y = h2u(r1);
                    *(uint2*)&sm[AS_OFF + swzc(al, l5 * 2)] = o;
                }
            }
        }
        __syncthreads();                                      // (1) As + W2 ready
        stage_sw(&sm[WB_OFF], w3p, 2048, tid);                // W3 under gemm2
        {   // Ts = ssp(As @ W2 + b2)
            f32x4 acc[2] = {{0,0,0,0},{0,0,0,0}};
            run_gemm_sw<2>(&sm[AS_OFF], &sm[WA_OFF], lane, w * 32, acc);
            #pragma unroll
            for (int ct = 0; ct < 2; ++ct) {
                int n = w * 32 + ct * 16 + m;
                float bv = b2[n];
                #pragma unroll
                for (int i = 0; i < 4; ++i) {
                    float v = ssp(acc[ct][i] + bv);
                    float u = __shfl_xor(v, 1, 64);
                    if (!(lane & 1))
                        sm[TS_OFF + swzc(q * 4 + i, n >> 1)] = pack2(v, u);
                }
            }
        }
        __syncthreads();                                      // (2) Ts + W3 ready
        stage_sw(&sm[WA_OFF], w1np, last ? 1024 : 2048, tid); // W1n/ow1 under gemm3
        {   // h += Ts @ W3 + b3 (registers only) ; As <- h_new (f16)
            f32x4 acc[2] = {{0,0,0,0},{0,0,0,0}};
            run_gemm_sw<2>(&sm[TS_OFF], &sm[WB_OFF], lane, w * 32, acc);
            #pragma unroll
            for (int ct = 0; ct < 2; ++ct) {
                int n = w * 32 + ct * 16 + m;
                float bv = b3[n];
                #pragma unroll
                for (int i = 0; i < 4; ++i) {
                    float hv = hr[ct][i] + acc[ct][i] + bv;
                    hr[ct][i] = hv;
                    float u = __shfl_xor(hv, 1, 64);
                    if (!(lane & 1))
                        sm[AS_OFF + swzc(q * 4 + i, n >> 1)] = pack2(hv, u);
                }
            }
        }
        __syncthreads();                                      // (3) As(h) + W1n ready
        if (!last) {
            f32x4 acc[2] = {{0,0,0,0},{0,0,0,0}};
            run_gemm_sw<2>(&sm[AS_OFF], &sm[WA_OFF], lane, w * 32, acc);
            #pragma unroll
            for (int ct = 0; ct < 2; ++ct) {
                int n = w * 32 + ct * 16 + m;
                #pragma unroll
                for (int i = 0; i < 4; ++i) {
                    float v = acc[ct][i];
                    float u = __shfl_xor(v, 1, 64);
                    if (!(lane & 1))
                        xw[(rowbase + q * 4 + i) * 64 + (n >> 1)] = pack2(v, u);
                }
            }
            // ---- per-graph barrier: the 16 blocks of graph g ----
            __syncthreads();           // each wave drained vmcnt: xw stores in L2
            if (tid == 0) {
                uint* c = a.bar + l * NB + g;
                // RELEASE/agent: buffer_wbl2 sc1 + atomic -> stores agent-visible
                __hip_atomic_fetch_add(c, 1u, __ATOMIC_RELEASE, __HIP_MEMORY_SCOPE_AGENT);
                int it = 0;
                while (__hip_atomic_load(c, __ATOMIC_RELAXED, __HIP_MEMORY_SCOPE_AGENT) < 16u
                       && ++it < (1 << 18))
                    __builtin_amdgcn_s_sleep(1);
                // single ACQUIRE fence: buffer_inv sc1, refetch fresh x lines
                __builtin_amdgcn_fence(__ATOMIC_ACQUIRE, "agent");
            }
            __syncthreads();
            xr = xw; xw += X_STR;
        } else {
            f32x4 acc[1] = {{0,0,0,0}};
            run_gemm_sw<1>(&sm[AS_OFF], &sm[WA_OFF], lane, w * 16, acc);
            int n = w * 16 + m;
            float b1v = a.ob1[n], w2v = a.ow2[n];
            float part = 0.f;
            #pragma unroll
            for (int i = 0; i < 4; ++i) part += ssp(acc[0][i] + b1v) * w2v;
            #pragma unroll
            for (int mm = 1; mm < 64; mm <<= 1) part += __shfl_xor(part, mm, 64);
            float* fs = (float*)&sm[TS_OFF];
            if (lane == 0) fs[w] = part;
            __syncthreads();
            if (tid == 0) {
                float bsum = fs[0] + fs[1] + fs[2] + fs[3] + 16.0f * a.ob2[0];
                float add = 32.0f * bsum;
                if (sub == 0) {
                    float sb = 0.f;
                    for (int jj = 0; jj < NB; ++jj) sb += a.gbias[jj];
                    add += sb;
                }
                atomicAdd(&a.out[g], add);
            }
        }
    }
}

// ---------------------------------------------------------------------------
extern "C" void kernel_launch(void* const* d_in, const int* in_sizes, int n_in,
                              void* d_out, int out_size, void* d_ws, size_t ws_size,
                              hipStream_t stream) {
    SArgs a;
    a.pos  = (const float*)d_in[0];
    a.z    = (const int*)d_in[1];
    a.ei   = (const int*)d_in[3];
    a.dom  = (const int*)d_in[4];
    a.emb  = (const float*)d_in[5];
    a.mw1  = (const float*)d_in[6];
    a.mb1  = (const float*)d_in[7];
    a.mw2  = (const float*)d_in[8];
    a.mb2  = (const float*)d_in[9];
    a.cf1  = (const float*)d_in[10];
    a.cf2w = (const float*)d_in[11];
    const float* cf2b = (const float*)d_in[12];
    a.intw = (const float*)d_in[13];
    const float* intb = (const float*)d_in[14];
    a.ow1  = (const float*)d_in[15];
    const float* ob1  = (const float*)d_in[16];
    const float* ow2  = (const float*)d_in[17];
    const float* ob2  = (const float*)d_in[18];
    a.dome = (const float*)d_in[19];
    a.fw1  = (const float*)d_in[20];
    a.fb1  = (const float*)d_in[21];
    a.fw2  = (const float*)d_in[22];
    a.fb2  = (const float*)d_in[23];
    a.bw   = (const float*)d_in[26];
    a.bb   = (const float*)d_in[27];

    char* ws = (char*)d_ws;
    a.epack   = (uint2*)(ws + 0);               // 2 MB
    a.tab2    = (uint*)(ws + 2*MB);             // 3 MB (interleaved pairs)
    a.h       = (float*)(ws + 5*MB);            // 4 MB (embedding init only)
    a.xA      = (uint*)(ws + 9*MB);             // 2 MB (x_0)
    uint* xb  = (uint*)(ws + 11*MB);            // 10 MB (x_1..x_5)
    a.gbias   = (float*)(ws + 21*MB);           // 128 B
    a.bar     = (uint*)(ws + 21*MB + 4096);     // 1 KB counters
    a.wpack   = (uint*)(ws + 21*MB + 8192);     // 606 KB
    a.out = (float*)d_out;
    a.out_size = out_size;

    k_setup<<<NGRID, 256, 0, stream>>>(a);

    LArgs la;
    la.h = a.h; la.x0 = a.xA; la.xb = xb;
    la.tab2 = a.tab2; la.epack = a.epack; la.wpack = a.wpack;
    la.cf2b = cf2b; la.intb = intb;
    la.ob1 = ob1; la.ow2 = ow2; la.ob2 = ob2;
    la.gbias = a.gbias; la.out = (float*)d_out; la.bar = a.bar;

    k_fused<<<dim3(512), dim3(256), 0, stream>>>(la);
}

// Round 3
// 272.609 us; speedup vs baseline: 1.3404x; 1.3404x over previous
//
#include <hip/hip_runtime.h>
#include <math.h>

using uint = unsigned int;
typedef _Float16 h2    __attribute__((ext_vector_type(2)));
typedef _Float16 f16x8 __attribute__((ext_vector_type(8)));
typedef float    f32x4 __attribute__((ext_vector_type(4)));

#define N_ATOMS 8192
#define NEDGE   262144
#define KNBR    32
#define NGAUSS  50
#define NLAYER  6
#define NB      32
#define GTAB    1024
#define DMAX    8.6603f
#define FCUT    10.0f
#define MB      1048576

#define NSETUP  512

// ---- k_setup legacy LDS geometry (stride 76) ----
#define LSTRIDE 76
#define S_WT    0               // 128*76 = 9728
#define S_AS    9728            // 16*76 = 1216

// ---- k_fused swizzled LDS geometry (stride 64, quad ^= row&15) ----
#define WA_OFF  0               // 8192 uints (32 KB)
#define WB_OFF  8192            // 8192
#define AS_OFF  16384           // 1024 (16 rows x 64)
#define TS_OFF  17408           // 1024
#define LAY_N   18432           // 72 KB -> exactly 2 blocks/CU, 512 co-resident

// ---- k_table LDS ----
#define T_W1    0               // 4096
#define T_W2    4096            // 8192
#define T_RBF   12288           // 1024
#define T_HID   13312           // 2048
#define TAB_SMEM 15360

// wpack layout (uints): 18 mats 128x128 (c,kp): cf1 x6 | cf2 x6 | int x6, then ow1^T
#define OW1P_OFF 147456
#define PACK_END 151552         // mlp_w1/w2 not packed (k_table reads raw floats)
#define X_STR    524288         // 2 MB of uints per per-layer x buffer

__device__ __forceinline__ float ssp(float x) {
    return fmaxf(x, 0.0f) + log1pf(expf(-fabsf(x))) - 0.69314718055994531f;
}
__device__ __forceinline__ uint pack2(float a, float b) {
    union { h2 h; uint u; } x;
    h2 v; v.x = (_Float16)a; v.y = (_Float16)b; x.h = v; return x.u;
}
__device__ __forceinline__ h2 u2h(uint u) {
    union { uint u; h2 h; } x; x.u = u; return x.h;
}
__device__ __forceinline__ uint h2u(h2 h) {
    union { h2 h; uint u; } x; x.h = h; return x.u;
}
__device__ __forceinline__ float fdot2f(h2 a, h2 b, float c) {
#if __has_builtin(__builtin_amdgcn_fdot2)
    return __builtin_amdgcn_fdot2(a, b, c, false);
#else
    return fmaf((float)a.y, (float)b.y, fmaf((float)a.x, (float)b.x, c));
#endif
}

// ---- swizzled indexing: row-stride 64 uints, bank quad XORed with row&15 ----
__device__ __forceinline__ int swz(int row, int quad) {
    return row * 64 + ((quad ^ (row & 15)) << 2);
}
__device__ __forceinline__ int swzc(int row, int c) {   // c = uint column 0..63
    return row * 64 + (((c >> 2) ^ (row & 15)) << 2) + (c & 3);
}

// stage pre-packed W^T (c,kp) -> swizzled LDS region
__device__ __forceinline__ void stage_sw(uint* dst, const uint* __restrict__ src,
                                         int n16, int tid) {
    for (int i = tid; i < n16; i += 256) {
        uint4 v = ((const uint4*)src)[i];
        *(uint4*)&dst[swz(i >> 4, i & 15)] = v;
    }
}

// swizzled MFMA: D[16 rows][NCT*16 cols] = A(16x128) @ W^T, cols base nb
template<int NCT>
__device__ __forceinline__ void run_gemm_sw(const uint* smA, const uint* smW,
                                            int lane, int nb, f32x4* acc) {
    int m = lane & 15, q = lane >> 4;
    #pragma unroll
    for (int ks = 0; ks < 4; ++ks) {
        int cq = q + ks * 4;
        f16x8 a = *(const f16x8*)&smA[swz(m, cq)];
        #pragma unroll
        for (int ct = 0; ct < NCT; ++ct) {
            int n = nb + ct * 16 + m;
            f16x8 b = *(const f16x8*)&smW[swz(n, cq)];
            acc[ct] = __builtin_amdgcn_mfma_f32_16x16x32_f16(a, b, acc[ct], 0, 0, 0);
        }
    }
}

// legacy stride-76 gemm for k_setup x0
template<int NCT>
__device__ __forceinline__ void run_gemm(const uint* sm, int as_off, int lane,
                                         int nb, f32x4* acc) {
    int m = lane & 15, q = lane >> 4;
    #pragma unroll
    for (int ks = 0; ks < 4; ++ks) {
        f16x8 a = *(const f16x8*)&sm[as_off + m * LSTRIDE + q * 4 + ks * 16];
        #pragma unroll
        for (int ct = 0; ct < NCT; ++ct) {
            f16x8 b = *(const f16x8*)&sm[S_WT + (nb + ct * 16 + m) * LSTRIDE + q * 4 + ks * 16];
            acc[ct] = __builtin_amdgcn_mfma_f32_16x16x32_f16(a, b, acc[ct], 0, 0, 0);
        }
    }
}

struct SArgs {
    const float *pos; const int *z; const int *ei; const int *dom;
    const float *emb;
    const float *cf1; const float *cf2w; const float *intw; const float *ow1;
    const float *dome; const float *fw1; const float *fb1;
    const float *fw2; const float *fb2; const float *bw; const float *bb;
    uint2 *epack; float *h; uint *xA;
    float *gbias; uint *wpack; uint *bar;
    float *out; int out_size;
};

// ---------------------------------------------------------------------------
// setup: zero-out + wcvt + epack + embed + x0 GEMM + film (blocks 32..63)
__global__ void __launch_bounds__(256) k_setup(SArgs a) {
    __shared__ __align__(16) uint sm[S_AS + 1216];
    const int tid = threadIdx.x, bid = blockIdx.x;
    const int gidx = bid * 256 + tid, gsz = NSETUP * 256;
    const int lane = tid & 63, w = tid >> 6;
    const int m = lane & 15, q = lane >> 4;
    const int rowbase = bid * 16;

    for (int i = gidx; i < a.out_size; i += gsz) a.out[i] = 0.0f;
    if (gidx < 256) a.bar[gidx] = 0u;      // per-graph barrier counters

    for (int idx = gidx; idx < PACK_END; idx += gsz) {
        if (idx < OW1P_OFF) {
            int mat = idx >> 13, e = idx & 8191;
            int kp = e >> 7, cc = e & 127;
            const float* src = (mat < 6) ? (a.cf1 + mat * 16384)
                            : (mat < 12) ? (a.cf2w + (mat - 6) * 16384)
                                         : (a.intw + (mat - 12) * 16384);
            a.wpack[mat * 8192 + cc * 64 + kp] =
                pack2(src[2 * kp * 128 + cc], src[(2 * kp + 1) * 128 + cc]);
        } else {
            int e = idx - OW1P_OFF;
            int kp = e >> 6, cc = e & 63;
            a.wpack[OW1P_OFF + cc * 64 + kp] =
                pack2(a.ow1[2 * kp * 64 + cc], a.ow1[(2 * kp + 1) * 64 + cc]);
        }
    }

    const float invdelta = (float)(GTAB - 1) / DMAX;
    #pragma unroll
    for (int t = 0; t < 2; ++t) {
        int e = rowbase * KNBR + t * 256 + tid;
        int s = a.ei[e], d = a.ei[NEDGE + e];
        float dx = a.pos[3*s] - a.pos[3*d];
        float dy = a.pos[3*s+1] - a.pos[3*d+1];
        float dz = a.pos[3*s+2] - a.pos[3*d+2];
        float dist = sqrtf(dx*dx + dy*dy + dz*dz);
        float u = dist * invdelta;
        int i0 = (int)u; i0 = (i0 < GTAB - 2) ? i0 : (GTAB - 2);
        float t2 = u - (float)i0;
        uint tb = pack2(t2, 0.0f) & 0xffffu;
        uint2 ep; ep.x = (uint)s; ep.y = (tb << 16) | (uint)i0;
        a.epack[e] = ep;
    }

    for (int i = tid; i < 1024; i += 256) {
        int r = i >> 6, f2 = i & 63;
        int zz = a.z[rowbase + r];
        float2 v = *(const float2*)&a.emb[zz * 128 + f2 * 2];
        *(float2*)&a.h[(rowbase + r) * 128 + f2 * 2] = v;
        sm[S_AS + r * LSTRIDE + f2] = pack2(v.x, v.y);
    }
    for (int i = tid; i < 2048; i += 256) {
        int m4 = i >> 7, cc = i & 127;
        float v[8];
        #pragma unroll
        for (int j = 0; j < 8; ++j) v[j] = a.cf1[(8 * m4 + j) * 128 + cc];
        uint4 pk; pk.x = pack2(v[0], v[1]); pk.y = pack2(v[2], v[3]);
        pk.z = pack2(v[4], v[5]); pk.w = pack2(v[6], v[7]);
        *(uint4*)&sm[cc * LSTRIDE + m4 * 4] = pk;
    }
    __syncthreads();
    {   // x0 = h @ W1_0 -> xA
        f32x4 acc[2] = {{0,0,0,0},{0,0,0,0}};
        run_gemm<2>(sm, S_AS, lane, w * 32, acc);
        #pragma unroll
        for (int ct = 0; ct < 2; ++ct) {
            int n = w * 32 + ct * 16 + m;
            #pragma unroll
            for (int i = 0; i < 4; ++i) {
                float v = acc[ct][i];
                float u = __shfl_xor(v, 1, 64);
                if (!(lane & 1))
                    a.xA[(rowbase + q * 4 + i) * 64 + (n >> 1)] = pack2(v, u);
            }
        }
    }
    __syncthreads();
    if (bid >= 32 && bid < 64) {
        int g = bid - 32;
        float* fs = (float*)sm;
        if (tid < 64) fs[tid] = a.dome[a.dom[g] * 64 + tid];
        __syncthreads();
        if (tid < 128) {
            float acc = a.fb1[tid];
            for (int i = 0; i < 64; ++i) acc = fmaf(fs[i], a.fw1[i*128 + tid], acc);
            fs[64 + tid] = fmaxf(acc, 0.0f);
        }
        __syncthreads();
        if (tid < 128) {
            float acc = a.fb2[tid];
            for (int i = 0; i < 128; ++i) acc = fmaf(fs[64+i], a.fw2[i*128 + tid], acc);
            fs[192 + tid] = acc;
        }
        __syncthreads();
        if (tid < 128) {
            float acc = a.bb[tid];
            for (int i = 0; i < 128; ++i) acc = fmaf(fs[192+i], a.bw[i*128 + tid], acc);
            #pragma unroll
            for (int off = 32; off > 0; off >>= 1) acc += __shfl_down(acc, off, 64);
            if ((tid & 63) == 0) fs[320 + (tid >> 6)] = acc;
        }
        __syncthreads();
        if (tid == 0) a.gbias[g] = fs[320] + fs[321];
    }
}

// ---------------------------------------------------------------------------
// filter tables, standalone; reads RAW mlp_w1/w2 floats (no wpack dependency)
__global__ void __launch_bounds__(256) k_table(
    const float* __restrict__ mw1, const float* __restrict__ mb1,
    const float* __restrict__ mw2, const float* __restrict__ mb2,
    uint* __restrict__ tab2) {
    __shared__ __align__(16) uint sm[TAB_SMEM];
    const int tid = threadIdx.x;
    const int l = blockIdx.x >> 5;
    const int base = (blockIdx.x & 31) * 32;
    for (int i = tid; i < 4096; i += 256) {      // W1 (kp,c), kp 0..31
        int kp = i >> 7, cc = i & 127, g0 = 2 * kp;
        float va = (g0 < NGAUSS)     ? mw1[l*NGAUSS*128 + g0*128 + cc]     : 0.f;
        float vb = (g0 + 1 < NGAUSS) ? mw1[l*NGAUSS*128 + (g0+1)*128 + cc] : 0.f;
        sm[T_W1 + i] = pack2(va, vb);
    }
    for (int i = tid; i < 8192; i += 256) {      // W2 (kp,c), kp 0..63
        int kp = i >> 7, cc = i & 127;
        sm[T_W2 + i] = pack2(mw2[l*16384 + 2*kp*128 + cc],
                             mw2[l*16384 + (2*kp+1)*128 + cc]);
    }
    const float delta = DMAX / (float)(GTAB - 1);
    const float gstep = FCUT / (float)(NGAUSS - 1);
    const float coeff = -0.5f / (gstep * gstep);
    for (int i = tid; i < 1024; i += 256) {
        int r = i >> 5, kp = i & 31;
        float dv = (float)(base + r) * delta;
        int g0 = 2 * kp;
        float v0 = 0.f, v1 = 0.f;
        if (g0 < NGAUSS)     { float t = dv - (float)g0 * gstep;     v0 = expf(coeff*t*t); }
        if (g0 + 1 < NGAUSS) { float t = dv - (float)(g0+1) * gstep; v1 = expf(coeff*t*t); }
        sm[T_RBF + i] = pack2(v0, v1);
    }
    __syncthreads();
    int tx = tid & 31, ty = tid >> 5, c0 = tx * 4, tr0 = ty * 4;
    float acc[4][4];
    #pragma unroll
    for (int i = 0; i < 4; ++i) { acc[i][0]=0.f; acc[i][1]=0.f; acc[i][2]=0.f; acc[i][3]=0.f; }
    #pragma unroll
    for (int oct = 0; oct < 8; ++oct) {
        int kp0 = oct * 4;
        uint4 w_[4];
        #pragma unroll
        for (int p = 0; p < 4; ++p) w_[p] = *(const uint4*)&sm[T_W1 + (kp0+p)*128 + c0];
        #pragma unroll
        for (int i = 0; i < 4; ++i) {
            uint4 av = *(const uint4*)&sm[T_RBF + (tr0+i)*32 + kp0];
            uint aa[4] = {av.x, av.y, av.z, av.w};
            #pragma unroll
            for (int p = 0; p < 4; ++p) {
                h2 ap = u2h(aa[p]);
                acc[i][0] = fdot2f(ap, u2h(w_[p].x), acc[i][0]);
                acc[i][1] = fdot2f(ap, u2h(w_[p].y), acc[i][1]);
                acc[i][2] = fdot2f(ap, u2h(w_[p].z), acc[i][2]);
                acc[i][3] = fdot2f(ap, u2h(w_[p].w), acc[i][3]);
            }
        }
    }
    float4 b1v = *(const float4*)&mb1[l*128 + c0];
    #pragma unroll
    for (int i = 0; i < 4; ++i) {
        uint2 o;
        o.x = pack2(ssp(acc[i][0] + b1v.x), ssp(acc[i][1] + b1v.y));
        o.y = pack2(ssp(acc[i][2] + b1v.z), ssp(acc[i][3] + b1v.w));
        *(uint2*)&sm[T_HID + (tr0+i)*64 + (c0 >> 1)] = o;
    }
    __syncthreads();
    float acc2[4][4];
    #pragma unroll
    for (int i = 0; i < 4; ++i) { acc2[i][0]=0.f; acc2[i][1]=0.f; acc2[i][2]=0.f; acc2[i][3]=0.f; }
    #pragma unroll 4
    for (int oct = 0; oct < 16; ++oct) {
        int kp0 = oct * 4;
        uint4 w_[4];
        #pragma unroll
        for (int p = 0; p < 4; ++p) w_[p] = *(const uint4*)&sm[T_W2 + (kp0+p)*128 + c0];
        #pragma unroll
        for (int i = 0; i < 4; ++i) {
            uint4 av = *(const uint4*)&sm[T_HID + (tr0+i)*64 + kp0];
            uint aa[4] = {av.x, av.y, av.z, av.w};
            #pragma unroll
            for (int p = 0; p < 4; ++p) {
                h2 ap = u2h(aa[p]);
                acc2[i][0] = fdot2f(ap, u2h(w_[p].x), acc2[i][0]);
                acc2[i][1] = fdot2f(ap, u2h(w_[p].y), acc2[i][1]);
                acc2[i][2] = fdot2f(ap, u2h(w_[p].z), acc2[i][2]);
                acc2[i][3] = fdot2f(ap, u2h(w_[p].w), acc2[i][3]);
            }
        }
    }
    float4 b2v = *(const float4*)&mb2[l*128 + c0];
    #pragma unroll
    for (int i = 0; i < 4; ++i) {
        int row = base + tr0 + i;
        float dv = (float)row * delta;
        float Cd = 0.5f * (cosf(dv * 0.3141592653589793f) + 1.0f);
        uint2 o;
        o.x = pack2((acc2[i][0] + b2v.x)*Cd, (acc2[i][1] + b2v.y)*Cd);
        o.y = pack2((acc2[i][2] + b2v.z)*Cd, (acc2[i][3] + b2v.w)*Cd);
        *(uint2*)&tab2[(l*GTAB + row)*128 + tx*4] = o;
        if (row > 0)
            *(uint2*)&tab2[(l*GTAB + row - 1)*128 + tx*4 + 2] = o;
    }
}

struct LArgs {
    const float* h;
    const uint* x0;
    uint* xb;                 // x_1..x_5, X_STR uints apart
    const uint* tab2;
    const uint2* epack;
    const uint* wpack;
    const float* cf2b;
    const float* intb;
    const float* ob1; const float* ow2; const float* ob2;
    const float* gbias;
    float* out;
    uint* bar;                // [NLAYER-1][NB] arrive counters, zeroed by k_setup
};

// ---------------------------------------------------------------------------
// All 6 layers fused, regular launch; co-residency structural (72 KB LDS -> 2
// blocks/CU x 256 CU = 512 = grid). Per-graph barrier with NO cache-wide ops:
// all 16 blocks of graph g share one XCD (bid&7 placement), so x stores
// drained to the shared L2 by __syncthreads (write-through L1) are visible to
// consumers with no fence. The counter uses RELAXED SYSTEM-scope atomics
// (global_atomic/load sc0 sc1 — per-instruction bypass, NO buffer_wbl2 /
// buffer_inv), eliminating the round-1 L2-invalidation storm that starved the
// gather (MfmaUtil 0.8%, VALUBusy 19%). Each x address is written once per
// dispatch and read only post-barrier -> no stale-line hazard. Spin is bounded
// so any violated assumption fails finite instead of hanging.
__global__ void __launch_bounds__(256, 2) k_fused(LArgs a) {
    __shared__ __align__(16) uint sm[LAY_N];
    const int tid = threadIdx.x, bid = blockIdx.x;
    const int lane = tid & 63, w = tid >> 6;
    const int m = lane & 15, q = lane >> 4;
    const int xcd = bid & 7;
    const int j   = bid >> 3;
    const int g   = xcd * 4 + (j >> 4);
    const int sub = j & 15;
    const int rowbase = g * 256 + sub * 16;

    float hr[2][4];
    #pragma unroll
    for (int ct = 0; ct < 2; ++ct)
        #pragma unroll
        for (int i = 0; i < 4; ++i)
            hr[ct][i] = a.h[(rowbase + q * 4 + i) * 128 + w * 32 + ct * 16 + m];

    const uint* xr = a.x0;
    uint* xw = a.xb;

    #pragma unroll 1
    for (int l = 0; l < NLAYER; ++l) {
        const bool last = (l == NLAYER - 1);
        const uint* w2p  = a.wpack + (6 + l) * 8192;
        const uint* w3p  = a.wpack + (12 + l) * 8192;
        const uint* w1np = last ? (a.wpack + OW1P_OFF) : (a.wpack + (l + 1) * 8192);
        const uint* tabl = a.tab2 + l * (GTAB * 128);
        const float* b2 = a.cf2b + l * 128;
        const float* b3 = a.intb + l * 128;

        stage_sw(&sm[WA_OFF], w2p, 2048, tid);     // W2 loads fly under gather
        {   // gather 16 atoms (4/wave), 2 edges/iter per 32-lane side
            const int side = lane >> 5, l5 = lane & 31;
            #pragma unroll
            for (int p = 0; p < 4; ++p) {
                int al = p * 4 + w;
                uint2 ep = a.epack[(rowbase + al) * KNBR + l5];
                h2 a0; a0.x = (_Float16)0; a0.y = (_Float16)0;
                h2 a1 = a0;
                #pragma unroll 4
                for (int k = 0; k < 16; ++k) {
                    int e = 2 * k + side;
                    uint s = __shfl(ep.x, e, 64);
                    uint y = __shfl(ep.y, e, 64);
                    int i0 = (int)(y & 0xffffu);
                    uint th = y >> 16;
                    h2 t2 = u2h(th | (th << 16));
                    uint4 tv = *(const uint4*)&tabl[i0 * 128 + l5 * 4];
                    uint2 xv = *(const uint2*)&xr[(int)s * 64 + l5 * 2];
                    h2 w0 = u2h(tv.x) + t2 * (u2h(tv.z) - u2h(tv.x));
                    h2 w1 = u2h(tv.y) + t2 * (u2h(tv.w) - u2h(tv.y));
                    a0 = a0 + u2h(xv.x) * w0;
                    a1 = a1 + u2h(xv.y) * w1;
                }
                uint u0 = h2u(a0), u1 = h2u(a1);
                uint p0 = __shfl_xor(u0, 32, 64), p1 = __shfl_xor(u1, 32, 64);
                if (side == 0) {
                    h2 r0 = u2h(u0) + u2h(p0), r1 = u2h(u1) + u2h(p1);
                    uint2 o; o.x = h2u(r0); o.y = h2u(r1);
                    *(uint2*)&sm[AS_OFF + swzc(al, l5 * 2)] = o;
                }
            }
        }
        __syncthreads();                                      // (1) As + W2 ready
        stage_sw(&sm[WB_OFF], w3p, 2048, tid);                // W3 under gemm2
        {   // Ts = ssp(As @ W2 + b2)
            f32x4 acc[2] = {{0,0,0,0},{0,0,0,0}};
            run_gemm_sw<2>(&sm[AS_OFF], &sm[WA_OFF], lane, w * 32, acc);
            #pragma unroll
            for (int ct = 0; ct < 2; ++ct) {
                int n = w * 32 + ct * 16 + m;
                float bv = b2[n];
                #pragma unroll
                for (int i = 0; i < 4; ++i) {
                    float v = ssp(acc[ct][i] + bv);
                    float u = __shfl_xor(v, 1, 64);
                    if (!(lane & 1))
                        sm[TS_OFF + swzc(q * 4 + i, n >> 1)] = pack2(v, u);
                }
            }
        }
        __syncthreads();                                      // (2) Ts + W3 ready
        stage_sw(&sm[WA_OFF], w1np, last ? 1024 : 2048, tid); // W1n/ow1 under gemm3
        {   // h += Ts @ W3 + b3 (registers only) ; As <- h_new (f16)
            f32x4 acc[2] = {{0,0,0,0},{0,0,0,0}};
            run_gemm_sw<2>(&sm[TS_OFF], &sm[WB_OFF], lane, w * 32, acc);
            #pragma unroll
            for (int ct = 0; ct < 2; ++ct) {
                int n = w * 32 + ct * 16 + m;
                float bv = b3[n];
                #pragma unroll
                for (int i = 0; i < 4; ++i) {
                    float hv = hr[ct][i] + acc[ct][i] + bv;
                    hr[ct][i] = hv;
                    float u = __shfl_xor(hv, 1, 64);
                    if (!(lane & 1))
                        sm[AS_OFF + swzc(q * 4 + i, n >> 1)] = pack2(hv, u);
                }
            }
        }
        __syncthreads();                                      // (3) As(h) + W1n ready
        if (!last) {
            f32x4 acc[2] = {{0,0,0,0},{0,0,0,0}};
            run_gemm_sw<2>(&sm[AS_OFF], &sm[WA_OFF], lane, w * 32, acc);
            #pragma unroll
            for (int ct = 0; ct < 2; ++ct) {
                int n = w * 32 + ct * 16 + m;
                #pragma unroll
                for (int i = 0; i < 4; ++i) {
                    float v = acc[ct][i];
                    float u = __shfl_xor(v, 1, 64);
                    if (!(lane & 1))
                        xw[(rowbase + q * 4 + i) * 64 + (n >> 1)] = pack2(v, u);
                }
            }
            // ---- per-graph barrier (16 same-XCD blocks), no cache-wide ops ----
            __syncthreads();           // waves drained vmcnt: xw stores in shared L2
            if (tid == 0) {
                uint* c = a.bar + l * NB + g;
                __hip_atomic_fetch_add(c, 1u, __ATOMIC_RELAXED,
                                       __HIP_MEMORY_SCOPE_SYSTEM);
                int it = 0;
                while (__hip_atomic_load(c, __ATOMIC_RELAXED,
                                         __HIP_MEMORY_SCOPE_SYSTEM) < 16u
                       && ++it < (1 << 18))
                    __builtin_amdgcn_s_sleep(2);
            }
            __syncthreads();
            xr = xw; xw += X_STR;
        } else {
            f32x4 acc[1] = {{0,0,0,0}};
            run_gemm_sw<1>(&sm[AS_OFF], &sm[WA_OFF], lane, w * 16, acc);
            int n = w * 16 + m;
            float b1v = a.ob1[n], w2v = a.ow2[n];
            float part = 0.f;
            #pragma unroll
            for (int i = 0; i < 4; ++i) part += ssp(acc[0][i] + b1v) * w2v;
            #pragma unroll
            for (int mm = 1; mm < 64; mm <<= 1) part += __shfl_xor(part, mm, 64);
            float* fs = (float*)&sm[TS_OFF];
            if (lane == 0) fs[w] = part;
            __syncthreads();
            if (tid == 0) {
                float bsum = fs[0] + fs[1] + fs[2] + fs[3] + 16.0f * a.ob2[0];
                float add = 32.0f * bsum;
                if (sub == 0) {
                    float sb = 0.f;
                    for (int jj = 0; jj < NB; ++jj) sb += a.gbias[jj];
                    add += sb;
                }
                atomicAdd(&a.out[g], add);
            }
        }
    }
}

// ---------------------------------------------------------------------------
extern "C" void kernel_launch(void* const* d_in, const int* in_sizes, int n_in,
                              void* d_out, int out_size, void* d_ws, size_t ws_size,
                              hipStream_t stream) {
    SArgs a;
    a.pos  = (const float*)d_in[0];
    a.z    = (const int*)d_in[1];
    a.ei   = (const int*)d_in[3];
    a.dom  = (const int*)d_in[4];
    a.emb  = (const float*)d_in[5];
    const float* mw1 = (const float*)d_in[6];
    const float* mb1 = (const float*)d_in[7];
    const float* mw2 = (const float*)d_in[8];
    const float* mb2 = (const float*)d_in[9];
    a.cf1  = (const float*)d_in[10];
    a.cf2w = (const float*)d_in[11];
    const float* cf2b = (const float*)d_in[12];
    a.intw = (const float*)d_in[13];
    const float* intb = (const float*)d_in[14];
    a.ow1  = (const float*)d_in[15];
    const float* ob1  = (const float*)d_in[16];
    const float* ow2  = (const float*)d_in[17];
    const float* ob2  = (const float*)d_in[18];
    a.dome = (const float*)d_in[19];
    a.fw1  = (const float*)d_in[20];
    a.fb1  = (const float*)d_in[21];
    a.fw2  = (const float*)d_in[22];
    a.fb2  = (const float*)d_in[23];
    a.bw   = (const float*)d_in[26];
    a.bb   = (const float*)d_in[27];

    char* ws = (char*)d_ws;
    a.epack   = (uint2*)(ws + 0);               // 2 MB
    uint* tab2= (uint*)(ws + 2*MB);             // 3 MB (interleaved pairs)
    a.h       = (float*)(ws + 5*MB);            // 4 MB (embedding init only)
    a.xA      = (uint*)(ws + 9*MB);             // 2 MB (x_0)
    uint* xb  = (uint*)(ws + 11*MB);            // 10 MB (x_1..x_5)
    a.gbias   = (float*)(ws + 21*MB);           // 128 B
    a.bar     = (uint*)(ws + 21*MB + 4096);     // 1 KB counters
    a.wpack   = (uint*)(ws + 21*MB + 8192);     // 606 KB
    a.out = (float*)d_out;
    a.out_size = out_size;

    k_setup<<<NSETUP, 256, 0, stream>>>(a);
    k_table<<<192, 256, 0, stream>>>(mw1, mb1, mw2, mb2, tab2);

    LArgs la;
    la.h = a.h; la.x0 = a.xA; la.xb = xb;
    la.tab2 = tab2; la.epack = a.epack; la.wpack = a.wpack;
    la.cf2b = cf2b; la.intb = intb;
    la.ob1 = ob1; la.ow2 = ow2; la.ob2 = ob2;
    la.gbias = a.gbias; la.out = (float*)d_out; la.bar = a.bar;

    k_fused<<<dim3(512), dim3(256), 0, stream>>>(la);
}